// Round 10
// baseline (440.959 us; speedup 1.0000x reference)
//
#include <hip/hip_runtime.h>
#include <hip/hip_bf16.h>
#include <hip/hip_fp16.h>
#include <cstddef>
#include <stdint.h>
#include <math.h>

// ---------------------------------------------------------------------------
// GAT 3-layer forward on MI355X.
//   CSR: zero -> hist -> 3-kernel parallel scan -> fill -> wave bitonic sort
//   L1: split-bf16 MFMA GEMM (fp16 table) -> attn_fold(x) -> agg12
//       (softmax + 2-deep batched gather, emits actA fp32 + L2 es/ed fused)
//   L2: GEMM(actA) -> agg12 (emits actB16 fp16 + L3 es/ed fused)
//   L3: gather actB16 -> z fp16 (coalesced 1KB store) -> fp16-MFMA GEMM -> out
// ---------------------------------------------------------------------------

static __device__ __forceinline__ float lrelu(float x){ return x > 0.f ? x : 0.2f * x; }
static __device__ __forceinline__ float elu_f(float x){ return x > 0.f ? x : expm1f(x); }

typedef __bf16    bf16x8 __attribute__((ext_vector_type(8)));
typedef _Float16  f16x8  __attribute__((ext_vector_type(8)));
typedef float     f32x4  __attribute__((ext_vector_type(4)));

// ============================ CSR build ====================================
__global__ void zero_int_kernel(int* __restrict__ p, int n){
  int i = blockIdx.x * blockDim.x + threadIdx.x;
  if (i < n) p[i] = 0;
}

__global__ void hist_kernel(const int* __restrict__ dst, int* __restrict__ deg, int E){
  int e = blockIdx.x * blockDim.x + threadIdx.x;
  if (e < E) atomicAdd(&deg[dst[e]], 1);
}

__global__ __launch_bounds__(1024) void scan1_kernel(const int* __restrict__ deg,
    int* __restrict__ partial, int* __restrict__ blocksum, int N){
  __shared__ int wsum[16];
  const int tid = threadIdx.x, lane = tid & 63, wid = tid >> 6;
  const int i = blockIdx.x * 1024 + tid;
  int v = (i < N) ? deg[i] : 0;
  int incl = v;
  #pragma unroll
  for (int off = 1; off < 64; off <<= 1){
    int t = __shfl_up(incl, off);
    if (lane >= off) incl += t;
  }
  if (lane == 63) wsum[wid] = incl;
  __syncthreads();
  if (tid == 0){
    int run = 0;
    #pragma unroll
    for (int w = 0; w < 16; w++){ int t = wsum[w]; wsum[w] = run; run += t; }
    blocksum[blockIdx.x] = run;
  }
  __syncthreads();
  if (i < N) partial[i] = wsum[wid] + incl - v;
}

__global__ void scan2_kernel(int* __restrict__ blocksum, int nb){
  const int lane = threadIdx.x;
  int v = (lane < nb) ? blocksum[lane] : 0;
  int incl = v;
  #pragma unroll
  for (int off = 1; off < 64; off <<= 1){
    int t = __shfl_up(incl, off);
    if (lane >= off) incl += t;
  }
  if (lane < nb) blocksum[lane] = incl - v;
}

__global__ void scan3_kernel(const int* __restrict__ partial, const int* __restrict__ blocksum,
    int* __restrict__ row_start, int* __restrict__ cursor, int N, int E){
  const int i = blockIdx.x * blockDim.x + threadIdx.x;
  if (i < N){
    const int r = partial[i] + blocksum[i >> 10];
    row_start[i] = r;
    cursor[i] = r;
  }
  if (i == 0) row_start[N] = E;
}

__global__ void fill_kernel(const int* __restrict__ src, const int* __restrict__ dst,
    int* __restrict__ cursor, int* __restrict__ edge_src, int E){
  int e = blockIdx.x * blockDim.x + threadIdx.x;
  if (e < E){
    int p = atomicAdd(&cursor[dst[e]], 1);
    edge_src[p] = src[e];
  }
}

// deterministic order: ascending srcs. Wave bitonic for deg<=64 (the norm).
__global__ __launch_bounds__(256) void sort_kernel(
    const int* __restrict__ row_start, int* __restrict__ edge_src, int N){
  const int lane = threadIdx.x & 63;
  const int n = blockIdx.x * 4 + (threadIdx.x >> 6);
  if (n >= N) return;
  const int rs = row_start[n], deg = row_start[n + 1] - rs;
  if (deg <= 1) return;
  if (deg <= 64){
    int v = (lane < deg) ? edge_src[rs + lane] : 0x7FFFFFFF;
    #pragma unroll
    for (int k = 2; k <= 64; k <<= 1){
      #pragma unroll
      for (int j = k >> 1; j >= 1; j >>= 1){
        int partner = __shfl_xor(v, j);
        const bool up = ((lane & k) == 0);
        const bool keepmin = (((lane & j) == 0) == up);
        v = keepmin ? min(v, partner) : max(v, partner);
      }
    }
    if (lane < deg) edge_src[rs + lane] = v;
  } else if (lane == 0){
    for (int i = rs + 1; i < rs + deg; i++){
      int key = edge_src[i];
      int j = i - 1;
      while (j >= rs && edge_src[j] > key){ edge_src[j + 1] = edge_src[j]; j--; }
      edge_src[j + 1] = key;
    }
  }
}

// ====================== split-bf16 packing =================================
static __device__ __forceinline__ uint32_t pack_hi_lo(float a){
  uint32_t u  = __float_as_uint(a);
  uint32_t hb = (u + 0x7FFFu + ((u >> 16) & 1u)) & 0xFFFF0000u;  // bf16 RNE of a
  float lof   = a - __uint_as_float(hb);
  uint32_t ul = __float_as_uint(lof);
  uint32_t lb = (ul + 0x7FFFu + ((ul >> 16) & 1u)) >> 16;        // bf16 RNE of residual
  return (hb >> 16) | (lb << 16);
}

__global__ void split_pack_w_kernel(const float* __restrict__ W, uint32_t* __restrict__ P,
                                    int K, int N){
  const int n = blockIdx.x;
  const int k = threadIdx.x;
  P[(size_t)n * K + k] = pack_hi_lo(W[(size_t)k * N + n]);
}

// W3 reordered+transposed fp16, 0.25 head-mean folded.
__global__ void pack_w3r_h_kernel(const float* __restrict__ W3, __half* __restrict__ P){
  const int nout = blockIdx.x;
  const int kk   = threadIdx.x;
  const int h = kk >> 7, k = kk & 127;
  P[(size_t)nout * 512 + kk] = __float2half(0.25f * W3[(size_t)k * 512 + h * 128 + nout]);
}

// fold attention vectors into layer-input space: wes[h,k] = sum_d W[k,h*D+d]*a_s[h,d]
__global__ void fold_kernel(const float* __restrict__ W, const float* __restrict__ as_,
                            const float* __restrict__ ad_, float* __restrict__ wes,
                            float* __restrict__ wed, int K, int D){
  int gid = blockIdx.x * blockDim.x + threadIdx.x;
  if (gid >= 4 * K) return;
  int h = gid / K, k = gid - h * K;
  const float* wr = W + (size_t)k * (4 * D) + h * D;
  const float* sa = as_ + h * D;
  const float* da = ad_ + h * D;
  float ss = 0.f, sd = 0.f;
  for (int d = 0; d < D; d++){ float w = wr[d]; ss += w * sa[d]; sd += w * da[d]; }
  wes[h * K + k] = ss;
  wed[h * K + k] = sd;
}

// ====================== MFMA GEMM (split-bf16, 3 mfma) =====================
union PKU { uint32_t u[4]; bf16x8 v; };

static __device__ __forceinline__ void unpack_frag(const uint4 q0, const uint4 q1,
                                                   bf16x8& hi, bf16x8& lo){
  PKU H, L;
  H.u[0] = (q0.x & 0xFFFFu) | (q0.y << 16);
  H.u[1] = (q0.z & 0xFFFFu) | (q0.w << 16);
  H.u[2] = (q1.x & 0xFFFFu) | (q1.y << 16);
  H.u[3] = (q1.z & 0xFFFFu) | (q1.w << 16);
  L.u[0] = (q0.x >> 16) | (q0.y & 0xFFFF0000u);
  L.u[1] = (q0.z >> 16) | (q0.w & 0xFFFF0000u);
  L.u[2] = (q1.x >> 16) | (q1.y & 0xFFFF0000u);
  L.u[3] = (q1.z >> 16) | (q1.w & 0xFFFF0000u);
  hi = H.v; lo = L.v;
}

// C = A@W (L1/L2). A fp32 [M,K] (packed in-register), Wpk [Nout,K] packed.
__global__ __launch_bounds__(256) void gemm_mfma_kernel(
    const float* __restrict__ A, const uint32_t* __restrict__ Wpk,
    __half* __restrict__ Ch, float* __restrict__ Cf, int M, int K, int Nout)
{
  __shared__ uint32_t Asl[4096];   // [128 rows][32 k] u32, XOR-swizzled
  __shared__ uint32_t Bsl[4096];
  const int tid  = threadIdx.x;
  const int lane = tid & 63;
  const int wid  = tid >> 6;
  const int wm   = (wid >> 1) * 64;
  const int wn   = (wid & 1) * 64;
  const int bm   = blockIdx.x * 128;
  const int bn   = blockIdx.y * 128;
  const int srow = tid >> 3;
  const int skof = (tid & 7) * 4;
  const int fr   = lane & 15;
  const int kg   = (lane >> 4) * 8;

  f32x4 acc[4][4] = {};

  for (int kt = 0; kt < K; kt += 32){
    float4 av[4]; uint4 bv[4];
    #pragma unroll
    for (int it = 0; it < 4; it++){
      const int r = srow + it * 32;
      av[it] = (bm + r < M)
          ? *reinterpret_cast<const float4*>(A + (size_t)(bm + r) * K + kt + skof)
          : make_float4(0.f, 0.f, 0.f, 0.f);
      bv[it] = *reinterpret_cast<const uint4*>(Wpk + (size_t)(bn + r) * K + kt + skof);
    }
    __syncthreads();
    #pragma unroll
    for (int it = 0; it < 4; it++){
      const int r  = srow + it * 32;
      const int sw = (r * 32 + skof) ^ ((r & 7) << 2);
      uint4 pv;
      pv.x = pack_hi_lo(av[it].x); pv.y = pack_hi_lo(av[it].y);
      pv.z = pack_hi_lo(av[it].z); pv.w = pack_hi_lo(av[it].w);
      *reinterpret_cast<uint4*>(&Asl[sw]) = pv;
      *reinterpret_cast<uint4*>(&Bsl[sw]) = bv[it];
    }
    __syncthreads();

    bf16x8 Ah[4], Al[4];
    #pragma unroll
    for (int mf = 0; mf < 4; mf++){
      const int r  = wm + mf * 16 + fr;
      const int b  = r * 32 + kg;
      const int sx = (r & 7) << 2;
      const uint4 q0 = *reinterpret_cast<const uint4*>(&Asl[b ^ sx]);
      const uint4 q1 = *reinterpret_cast<const uint4*>(&Asl[(b + 4) ^ sx]);
      unpack_frag(q0, q1, Ah[mf], Al[mf]);
    }
    #pragma unroll
    for (int nf = 0; nf < 4; nf++){
      const int r  = wn + nf * 16 + fr;
      const int b  = r * 32 + kg;
      const int sx = (r & 7) << 2;
      const uint4 q0 = *reinterpret_cast<const uint4*>(&Bsl[b ^ sx]);
      const uint4 q1 = *reinterpret_cast<const uint4*>(&Bsl[(b + 4) ^ sx]);
      bf16x8 Bh, Bl;
      unpack_frag(q0, q1, Bh, Bl);
      #pragma unroll
      for (int mf = 0; mf < 4; mf++){
        acc[mf][nf] = __builtin_amdgcn_mfma_f32_16x16x32_bf16(Al[mf], Bh, acc[mf][nf], 0, 0, 0);
        acc[mf][nf] = __builtin_amdgcn_mfma_f32_16x16x32_bf16(Ah[mf], Bl, acc[mf][nf], 0, 0, 0);
        acc[mf][nf] = __builtin_amdgcn_mfma_f32_16x16x32_bf16(Ah[mf], Bh, acc[mf][nf], 0, 0, 0);
      }
    }
  }

  #pragma unroll
  for (int mf = 0; mf < 4; mf++){
    #pragma unroll
    for (int nf = 0; nf < 4; nf++){
      const int col = bn + wn + nf * 16 + fr;
      #pragma unroll
      for (int j = 0; j < 4; j++){
        const int row = bm + wm + mf * 16 + (lane >> 4) * 4 + j;
        if (row < M){
          const float v = acc[mf][nf][j];
          if (Ch) Ch[(size_t)row * Nout + col] = __float2half(v);
          if (Cf) Cf[(size_t)row * Nout + col] = v;
        }
      }
    }
  }
}

// ============== fp16-MFMA GEMM for the final z@W3r (K=512) ================
__global__ __launch_bounds__(256) void gemm_f16_kernel(
    const __half* __restrict__ Zh, const __half* __restrict__ W3h,
    float* __restrict__ C, int M)
{
  constexpr int LDA = 40;
  __shared__ __half As[64 * LDA];
  __shared__ __half Bs[128 * LDA];
  const int tid  = threadIdx.x;
  const int lane = tid & 63;
  const int wid  = tid >> 6;
  const int wm   = (wid >> 1) * 32;
  const int wn   = (wid & 1) * 64;
  const int bm   = blockIdx.x * 64;
  const int fr   = lane & 15;
  const int kg   = (lane >> 4) * 8;
  const int arow = tid >> 2;
  const int akc  = (tid & 3) * 8;

  f32x4 acc[2][4] = {};

  for (int kt = 0; kt < 512; kt += 32){
    const uint4 a  = *reinterpret_cast<const uint4*>(Zh  + (size_t)(bm + arow) * 512 + kt + akc);
    const uint4 b0 = *reinterpret_cast<const uint4*>(W3h + (size_t)arow        * 512 + kt + akc);
    const uint4 b1 = *reinterpret_cast<const uint4*>(W3h + (size_t)(arow + 64) * 512 + kt + akc);
    __syncthreads();
    *reinterpret_cast<uint4*>(&As[arow * LDA + akc])        = a;
    *reinterpret_cast<uint4*>(&Bs[arow * LDA + akc])        = b0;
    *reinterpret_cast<uint4*>(&Bs[(arow + 64) * LDA + akc]) = b1;
    __syncthreads();

    f16x8 af[2], bf[4];
    #pragma unroll
    for (int mf = 0; mf < 2; mf++)
      af[mf] = *reinterpret_cast<const f16x8*>(&As[(wm + mf * 16 + fr) * LDA + kg]);
    #pragma unroll
    for (int nf = 0; nf < 4; nf++)
      bf[nf] = *reinterpret_cast<const f16x8*>(&Bs[(wn + nf * 16 + fr) * LDA + kg]);
    #pragma unroll
    for (int mf = 0; mf < 2; mf++)
      #pragma unroll
      for (int nf = 0; nf < 4; nf++)
        acc[mf][nf] = __builtin_amdgcn_mfma_f32_16x16x32_f16(af[mf], bf[nf], acc[mf][nf], 0, 0, 0);
  }

  #pragma unroll
  for (int mf = 0; mf < 2; mf++){
    #pragma unroll
    for (int nf = 0; nf < 4; nf++){
      const int col = wn + nf * 16 + fr;
      #pragma unroll
      for (int j = 0; j < 4; j++){
        const int row = bm + wm + mf * 16 + (lane >> 4) * 4 + j;
        if (row < M) C[(size_t)row * 128 + col] = acc[mf][nf][j];
      }
    }
  }
}

// ================= attention coefs from folded weights (layer 1) ===========
template<int K>
__global__ __launch_bounds__(256) void attn_fold_kernel(
    const float* __restrict__ in, const float* __restrict__ wes, const float* __restrict__ wed,
    float* __restrict__ es, float* __restrict__ ed, int N)
{
  int gid = blockIdx.x * blockDim.x + threadIdx.x;
  int n = gid >> 2, h = gid & 3;
  if (n >= N) return;
  const float* ip = in + (size_t)n * K;
  const float* sp = wes + h * K;
  const float* dp = wed + h * K;
  float ss = 0.f, sd = 0.f;
  #pragma unroll
  for (int d = 0; d < K; d += 4){
    float4 hv = *reinterpret_cast<const float4*>(ip + d);
    float4 sv = *reinterpret_cast<const float4*>(sp + d);
    float4 dv = *reinterpret_cast<const float4*>(dp + d);
    ss += hv.x * sv.x + hv.y * sv.y + hv.z * sv.z + hv.w * sv.w;
    sd += hv.x * dv.x + hv.y * dv.y + hv.z * dv.z + hv.w * dv.w;
  }
  es[n * 4 + h] = ss;
  ed[n * 4 + h] = sd;
}

// ==================== aggregate: layers 1/2 (fp16 table, concat+ELU) =======
// 2-deep batched gather (8 edges per outer iter, 2 loads in flight).
// Emits optional fp32 out + optional fp16 out16, and FUSED next-layer es/ed.
__global__ __launch_bounds__(256) void aggregate12_kernel(
    const int* __restrict__ row_start, const int* __restrict__ edge_src,
    const __half* __restrict__ hbuf, const float* __restrict__ es, const float* __restrict__ ed,
    float* __restrict__ out, __half* __restrict__ out16,
    const float* __restrict__ wesN, const float* __restrict__ wedN,
    float* __restrict__ esOut, float* __restrict__ edOut, int N)
{
  const int lane = threadIdx.x & 63;
  const int n = blockIdx.x * 4 + (threadIdx.x >> 6);
  if (n >= N) return;
  const int rs  = row_start[n];
  const int deg = row_start[n + 1] - rs;
  const float4 ed4 = *reinterpret_cast<const float4*>(&ed[n * 4]);
  const int sub  = lane >> 4;
  const int cl   = lane & 15;
  const int head = cl >> 2;
  float acc[8] = {0.f, 0.f, 0.f, 0.f, 0.f, 0.f, 0.f, 0.f};

  auto gather = [&](int cnt, int s_reg, float a0, float a1, float a2, float a3){
    for (int j = 0; j < cnt; j += 8){
      uint4 raw[2]; float alv[2];
      #pragma unroll
      for (int t = 0; t < 2; t++){
        const int  el    = j + t * 4 + sub;
        const bool valid = el < cnt;
        const int  ei    = valid ? el : 0;
        const int  s     = __shfl(s_reg, ei);
        const float b0 = __shfl(a0, ei), b1 = __shfl(a1, ei);
        const float b2 = __shfl(a2, ei), b3 = __shfl(a3, ei);
        float al = head == 0 ? b0 : head == 1 ? b1 : head == 2 ? b2 : b3;
        alv[t] = valid ? al : 0.f;
        raw[t] = *reinterpret_cast<const uint4*>(hbuf + (size_t)s * 128 + cl * 8);
      }
      #pragma unroll
      for (int t = 0; t < 2; t++){
        const __half2* hp = reinterpret_cast<const __half2*>(&raw[t]);
        #pragma unroll
        for (int q = 0; q < 4; q++){
          float2 f = __half22float2(hp[q]);
          acc[q * 2]     = fmaf(f.x, alv[t], acc[q * 2]);
          acc[q * 2 + 1] = fmaf(f.y, alv[t], acc[q * 2 + 1]);
        }
      }
    }
  };

  if (deg <= 64){
    int   s_reg = 0;
    float e0 = -INFINITY, e1 = -INFINITY, e2 = -INFINITY, e3 = -INFINITY;
    if (lane < deg){
      s_reg = edge_src[rs + lane];
      const float4 e4 = *reinterpret_cast<const float4*>(&es[s_reg * 4]);
      e0 = lrelu(e4.x + ed4.x); e1 = lrelu(e4.y + ed4.y);
      e2 = lrelu(e4.z + ed4.z); e3 = lrelu(e4.w + ed4.w);
    }
    float mx0 = e0, mx1 = e1, mx2 = e2, mx3 = e3;
    #pragma unroll
    for (int off = 1; off < 64; off <<= 1){
      mx0 = fmaxf(mx0, __shfl_xor(mx0, off)); mx1 = fmaxf(mx1, __shfl_xor(mx1, off));
      mx2 = fmaxf(mx2, __shfl_xor(mx2, off)); mx3 = fmaxf(mx3, __shfl_xor(mx3, off));
    }
    float p0 = 0.f, p1 = 0.f, p2 = 0.f, p3 = 0.f;
    if (lane < deg){
      p0 = __expf(e0 - mx0); p1 = __expf(e1 - mx1);
      p2 = __expf(e2 - mx2); p3 = __expf(e3 - mx3);
    }
    float s0 = p0, s1 = p1, s2 = p2, s3 = p3;
    #pragma unroll
    for (int off = 1; off < 64; off <<= 1){
      s0 += __shfl_xor(s0, off); s1 += __shfl_xor(s1, off);
      s2 += __shfl_xor(s2, off); s3 += __shfl_xor(s3, off);
    }
    gather(deg, s_reg,
           p0 / (s0 + 1e-16f), p1 / (s1 + 1e-16f),
           p2 / (s2 + 1e-16f), p3 / (s3 + 1e-16f));
  } else {
    float mx0 = -INFINITY, mx1 = -INFINITY, mx2 = -INFINITY, mx3 = -INFINITY;
    for (int i = lane; i < deg; i += 64){
      int s = edge_src[rs + i];
      float4 e4 = *reinterpret_cast<const float4*>(&es[s * 4]);
      mx0 = fmaxf(mx0, lrelu(e4.x + ed4.x)); mx1 = fmaxf(mx1, lrelu(e4.y + ed4.y));
      mx2 = fmaxf(mx2, lrelu(e4.z + ed4.z)); mx3 = fmaxf(mx3, lrelu(e4.w + ed4.w));
    }
    #pragma unroll
    for (int off = 1; off < 64; off <<= 1){
      mx0 = fmaxf(mx0, __shfl_xor(mx0, off)); mx1 = fmaxf(mx1, __shfl_xor(mx1, off));
      mx2 = fmaxf(mx2, __shfl_xor(mx2, off)); mx3 = fmaxf(mx3, __shfl_xor(mx3, off));
    }
    float s0 = 0.f, s1 = 0.f, s2 = 0.f, s3 = 0.f;
    for (int i = lane; i < deg; i += 64){
      int s = edge_src[rs + i];
      float4 e4 = *reinterpret_cast<const float4*>(&es[s * 4]);
      s0 += __expf(lrelu(e4.x + ed4.x) - mx0); s1 += __expf(lrelu(e4.y + ed4.y) - mx1);
      s2 += __expf(lrelu(e4.z + ed4.z) - mx2); s3 += __expf(lrelu(e4.w + ed4.w) - mx3);
    }
    #pragma unroll
    for (int off = 1; off < 64; off <<= 1){
      s0 += __shfl_xor(s0, off); s1 += __shfl_xor(s1, off);
      s2 += __shfl_xor(s2, off); s3 += __shfl_xor(s3, off);
    }
    const float inv0 = 1.f / (s0 + 1e-16f), inv1 = 1.f / (s1 + 1e-16f);
    const float inv2 = 1.f / (s2 + 1e-16f), inv3 = 1.f / (s3 + 1e-16f);
    for (int base = 0; base < deg; base += 64){
      const int cnt = min(64, deg - base);
      int s_reg = 0; float a0 = 0.f, a1 = 0.f, a2 = 0.f, a3 = 0.f;
      if (lane < cnt){
        s_reg = edge_src[rs + base + lane];
        const float4 e4 = *reinterpret_cast<const float4*>(&es[s_reg * 4]);
        a0 = __expf(lrelu(e4.x + ed4.x) - mx0) * inv0;
        a1 = __expf(lrelu(e4.y + ed4.y) - mx1) * inv1;
        a2 = __expf(lrelu(e4.z + ed4.z) - mx2) * inv2;
        a3 = __expf(lrelu(e4.w + ed4.w) - mx3) * inv3;
      }
      gather(cnt, s_reg, a0, a1, a2, a3);
    }
  }

  #pragma unroll
  for (int q = 0; q < 8; q++){
    acc[q] += __shfl_xor(acc[q], 16);
    acc[q] += __shfl_xor(acc[q], 32);
  }
  float o[8];
  #pragma unroll
  for (int q = 0; q < 8; q++) o[q] = elu_f(acc[q]);

  // fused next-layer attention coefs: subgroup h computes es/ed[n,h]
  {
    const int h = sub;
    float ssum = 0.f, dsum = 0.f;
    #pragma unroll
    for (int q = 0; q < 8; q++){
      ssum = fmaf(o[q], wesN[h * 128 + cl * 8 + q], ssum);
      dsum = fmaf(o[q], wedN[h * 128 + cl * 8 + q], dsum);
    }
    #pragma unroll
    for (int off = 1; off < 16; off <<= 1){
      ssum += __shfl_xor(ssum, off);
      dsum += __shfl_xor(dsum, off);
    }
    if (cl == 0){
      esOut[n * 4 + h] = ssum;
      edOut[n * 4 + h] = dsum;
    }
  }

  if (lane < 16){
    if (out){
      *reinterpret_cast<float4*>(&out[(size_t)n * 128 + lane * 8]) =
          make_float4(o[0], o[1], o[2], o[3]);
      *reinterpret_cast<float4*>(&out[(size_t)n * 128 + lane * 8 + 4]) =
          make_float4(o[4], o[5], o[6], o[7]);
    }
    if (out16){
      union { __half2 h2[4]; uint4 u; } pk;
      pk.h2[0] = __floats2half2_rn(o[0], o[1]);
      pk.h2[1] = __floats2half2_rn(o[2], o[3]);
      pk.h2[2] = __floats2half2_rn(o[4], o[5]);
      pk.h2[3] = __floats2half2_rn(o[6], o[7]);
      *reinterpret_cast<uint4*>(&out16[(size_t)n * 128 + lane * 8]) = pk.u;
    }
  }
}

// ========= aggregate layer 3: gather actB16 -> z[N,4,128] fp16 =============
// 2-deep batched gather; coalesced all-64-lane 1KB store per node.
__global__ __launch_bounds__(256) void aggregate3_pack_kernel(
    const int* __restrict__ row_start, const int* __restrict__ edge_src,
    const __half* __restrict__ tbl, const float* __restrict__ es, const float* __restrict__ ed,
    __half* __restrict__ Zh, int N)
{
  const int lane = threadIdx.x & 63;
  const int n = blockIdx.x * 4 + (threadIdx.x >> 6);
  if (n >= N) return;
  const int rs  = row_start[n];
  const int deg = row_start[n + 1] - rs;
  const float4 ed4 = *reinterpret_cast<const float4*>(&ed[n * 4]);
  const int sub = lane >> 4;
  const int cl  = lane & 15;
  float acc[4][8] = {};

  auto gather = [&](int cnt, int s_reg, float a0, float a1, float a2, float a3){
    for (int j = 0; j < cnt; j += 8){
      uint4 raw[2]; float alv[2][4];
      #pragma unroll
      for (int t = 0; t < 2; t++){
        const int  el    = j + t * 4 + sub;
        const bool valid = el < cnt;
        const int  ei    = valid ? el : 0;
        const int  s     = __shfl(s_reg, ei);
        const float b0 = __shfl(a0, ei), b1 = __shfl(a1, ei);
        const float b2 = __shfl(a2, ei), b3 = __shfl(a3, ei);
        alv[t][0] = valid ? b0 : 0.f; alv[t][1] = valid ? b1 : 0.f;
        alv[t][2] = valid ? b2 : 0.f; alv[t][3] = valid ? b3 : 0.f;
        raw[t] = *reinterpret_cast<const uint4*>(tbl + (size_t)s * 128 + cl * 8);
      }
      #pragma unroll
      for (int t = 0; t < 2; t++){
        const __half2* hp = reinterpret_cast<const __half2*>(&raw[t]);
        float f[8];
        #pragma unroll
        for (int q = 0; q < 4; q++){
          float2 v = __half22float2(hp[q]);
          f[q * 2] = v.x; f[q * 2 + 1] = v.y;
        }
        #pragma unroll
        for (int h = 0; h < 4; h++)
          #pragma unroll
          for (int q = 0; q < 8; q++)
            acc[h][q] = fmaf(f[q], alv[t][h], acc[h][q]);
      }
    }
  };

  if (deg <= 64){
    int   s_reg = 0;
    float e0 = -INFINITY, e1 = -INFINITY, e2 = -INFINITY, e3 = -INFINITY;
    if (lane < deg){
      s_reg = edge_src[rs + lane];
      const float4 e4 = *reinterpret_cast<const float4*>(&es[s_reg * 4]);
      e0 = lrelu(e4.x + ed4.x); e1 = lrelu(e4.y + ed4.y);
      e2 = lrelu(e4.z + ed4.z); e3 = lrelu(e4.w + ed4.w);
    }
    float mx0 = e0, mx1 = e1, mx2 = e2, mx3 = e3;
    #pragma unroll
    for (int off = 1; off < 64; off <<= 1){
      mx0 = fmaxf(mx0, __shfl_xor(mx0, off)); mx1 = fmaxf(mx1, __shfl_xor(mx1, off));
      mx2 = fmaxf(mx2, __shfl_xor(mx2, off)); mx3 = fmaxf(mx3, __shfl_xor(mx3, off));
    }
    float p0 = 0.f, p1 = 0.f, p2 = 0.f, p3 = 0.f;
    if (lane < deg){
      p0 = __expf(e0 - mx0); p1 = __expf(e1 - mx1);
      p2 = __expf(e2 - mx2); p3 = __expf(e3 - mx3);
    }
    float s0 = p0, s1 = p1, s2 = p2, s3 = p3;
    #pragma unroll
    for (int off = 1; off < 64; off <<= 1){
      s0 += __shfl_xor(s0, off); s1 += __shfl_xor(s1, off);
      s2 += __shfl_xor(s2, off); s3 += __shfl_xor(s3, off);
    }
    gather(deg, s_reg,
           p0 / (s0 + 1e-16f), p1 / (s1 + 1e-16f),
           p2 / (s2 + 1e-16f), p3 / (s3 + 1e-16f));
  } else {
    float mx0 = -INFINITY, mx1 = -INFINITY, mx2 = -INFINITY, mx3 = -INFINITY;
    for (int i = lane; i < deg; i += 64){
      int s = edge_src[rs + i];
      float4 e4 = *reinterpret_cast<const float4*>(&es[s * 4]);
      mx0 = fmaxf(mx0, lrelu(e4.x + ed4.x)); mx1 = fmaxf(mx1, lrelu(e4.y + ed4.y));
      mx2 = fmaxf(mx2, lrelu(e4.z + ed4.z)); mx3 = fmaxf(mx3, lrelu(e4.w + ed4.w));
    }
    #pragma unroll
    for (int off = 1; off < 64; off <<= 1){
      mx0 = fmaxf(mx0, __shfl_xor(mx0, off)); mx1 = fmaxf(mx1, __shfl_xor(mx1, off));
      mx2 = fmaxf(mx2, __shfl_xor(mx2, off)); mx3 = fmaxf(mx3, __shfl_xor(mx3, off));
    }
    float s0 = 0.f, s1 = 0.f, s2 = 0.f, s3 = 0.f;
    for (int i = lane; i < deg; i += 64){
      int s = edge_src[rs + i];
      float4 e4 = *reinterpret_cast<const float4*>(&es[s * 4]);
      s0 += __expf(lrelu(e4.x + ed4.x) - mx0); s1 += __expf(lrelu(e4.y + ed4.y) - mx1);
      s2 += __expf(lrelu(e4.z + ed4.z) - mx2); s3 += __expf(lrelu(e4.w + ed4.w) - mx3);
    }
    #pragma unroll
    for (int off = 1; off < 64; off <<= 1){
      s0 += __shfl_xor(s0, off); s1 += __shfl_xor(s1, off);
      s2 += __shfl_xor(s2, off); s3 += __shfl_xor(s3, off);
    }
    const float inv0 = 1.f / (s0 + 1e-16f), inv1 = 1.f / (s1 + 1e-16f);
    const float inv2 = 1.f / (s2 + 1e-16f), inv3 = 1.f / (s3 + 1e-16f);
    for (int base = 0; base < deg; base += 64){
      const int cnt = min(64, deg - base);
      int s_reg = 0; float a0 = 0.f, a1 = 0.f, a2 = 0.f, a3 = 0.f;
      if (lane < cnt){
        s_reg = edge_src[rs + base + lane];
        const float4 e4 = *reinterpret_cast<const float4*>(&es[s_reg * 4]);
        a0 = __expf(lrelu(e4.x + ed4.x) - mx0) * inv0;
        a1 = __expf(lrelu(e4.y + ed4.y) - mx1) * inv1;
        a2 = __expf(lrelu(e4.z + ed4.z) - mx2) * inv2;
        a3 = __expf(lrelu(e4.w + ed4.w) - mx3) * inv3;
      }
      gather(cnt, s_reg, a0, a1, a2, a3);
    }
  }

  #pragma unroll
  for (int h = 0; h < 4; h++)
    #pragma unroll
    for (int q = 0; q < 8; q++){
      acc[h][q] += __shfl_xor(acc[h][q], 16);
      acc[h][q] += __shfl_xor(acc[h][q], 32);
    }
  // every lane now holds complete sums; lane (sub,cl) stores head=sub at col cl
  {
    union { __half2 h2[4]; uint4 u; } pk;
    pk.h2[0] = __floats2half2_rn(acc[sub][0], acc[sub][1]);
    pk.h2[1] = __floats2half2_rn(acc[sub][2], acc[sub][3]);
    pk.h2[2] = __floats2half2_rn(acc[sub][4], acc[sub][5]);
    pk.h2[3] = __floats2half2_rn(acc[sub][6], acc[sub][7]);
    *reinterpret_cast<uint4*>(Zh + (size_t)n * 512 + sub * 128 + cl * 8) = pk.u;
  }
}

// =============================== driver ====================================
extern "C" void kernel_launch(void* const* d_in, const int* in_sizes, int n_in,
                              void* d_out, int out_size, void* d_ws, size_t ws_size,
                              hipStream_t stream) {
  const float* x   = (const float*)d_in[0];
  const int*   src = (const int*)  d_in[1];
  const int*   dst = (const int*)  d_in[2];
  const float* W1  = (const float*)d_in[3];
  const float* a1s = (const float*)d_in[4];
  const float* a1d = (const float*)d_in[5];
  const float* W2  = (const float*)d_in[6];
  const float* a2s = (const float*)d_in[7];
  const float* a2d = (const float*)d_in[8];
  const float* W3  = (const float*)d_in[9];
  const float* a3s = (const float*)d_in[10];
  const float* a3d = (const float*)d_in[11];

  const int N  = in_sizes[0] / 96;
  const int E  = in_sizes[1];
  const int Mp = (N + 127) & ~127;
  const int nb = (N + 1023) / 1024;

  char* ws = (char*)d_ws;
  auto alloc = [&](size_t bytes) -> void* {
    void* p = (void*)ws;
    ws += (bytes + 255) & ~(size_t)255;
    return p;
  };
  int*      row_start = (int*)     alloc((size_t)(N + 1) * 4);
  int*      cursor    = (int*)     alloc((size_t)N * 4);
  int*      blocksum  = (int*)     alloc((size_t)1024 * 4);
  int*      edge_src  = (int*)     alloc((size_t)E * 4);
  float*    esA       = (float*)   alloc((size_t)N * 4 * 4);
  float*    edA       = (float*)   alloc((size_t)N * 4 * 4);
  float*    esB       = (float*)   alloc((size_t)N * 4 * 4);
  float*    edB       = (float*)   alloc((size_t)N * 4 * 4);
  float*    wes1      = (float*)   alloc((size_t)4 * 128 * 4);
  float*    wed1      = (float*)   alloc((size_t)4 * 128 * 4);
  float*    wes2      = (float*)   alloc((size_t)4 * 128 * 4);
  float*    wed2      = (float*)   alloc((size_t)4 * 128 * 4);
  float*    wes3      = (float*)   alloc((size_t)4 * 128 * 4);
  float*    wed3      = (float*)   alloc((size_t)4 * 128 * 4);
  __half*   hbufH     = (__half*)  alloc((size_t)N * 128 * 2);   // L1/L2 gather table
  float*    actA      = (float*)   alloc((size_t)N * 128 * 4);
  __half*   actB16    = (__half*)  alloc((size_t)N * 128 * 2);   // L3 gather table
  __half*   Zh        = (__half*)  alloc((size_t)Mp * 512 * 2);  // fp16 z
  __half*   W3h       = (__half*)  alloc((size_t)128 * 512 * 2); // fp16 W3r
  uint32_t* Wpk       = (uint32_t*)alloc((size_t)128 * 128 * 4);

  // ---- CSR build ----
  zero_int_kernel<<<(N + 255) / 256, 256, 0, stream>>>(cursor, N);
  hist_kernel<<<(E + 255) / 256, 256, 0, stream>>>(dst, cursor, E);
  scan1_kernel<<<nb, 1024, 0, stream>>>(cursor, row_start, blocksum, N);
  scan2_kernel<<<1, 64, 0, stream>>>(blocksum, nb);
  scan3_kernel<<<(N + 255) / 256, 256, 0, stream>>>(row_start, blocksum, row_start, cursor, N, E);
  fill_kernel<<<(E + 255) / 256, 256, 0, stream>>>(src, dst, cursor, edge_src, E);
  sort_kernel<<<(N + 3) / 4, 256, 0, stream>>>(row_start, edge_src, N);

  const int aggGrid  = (N + 3) / 4;
  const int attnGrid = (N * 4 + 255) / 256;

  // ---- folds (all up front) ----
  fold_kernel<<<2, 256, 0, stream>>>(W1, a1s, a1d, wes1, wed1, 96, 32);
  fold_kernel<<<2, 256, 0, stream>>>(W2, a2s, a2d, wes2, wed2, 128, 32);
  fold_kernel<<<2, 256, 0, stream>>>(W3, a3s, a3d, wes3, wed3, 128, 128);

  // ---- layer 1: [N,96] @ [96,128] ----
  split_pack_w_kernel<<<128, 96, 0, stream>>>(W1, Wpk, 96, 128);
  gemm_mfma_kernel<<<dim3(Mp / 128, 1), 256, 0, stream>>>(x, Wpk, hbufH, (float*)nullptr, N, 96, 128);
  attn_fold_kernel<96><<<attnGrid, 256, 0, stream>>>(x, wes1, wed1, esA, edA, N);
  aggregate12_kernel<<<aggGrid, 256, 0, stream>>>(row_start, edge_src, hbufH, esA, edA,
                                                  actA, (__half*)nullptr, wes2, wed2, esB, edB, N);

  // ---- layer 2: [N,128] @ [128,128] ----
  split_pack_w_kernel<<<128, 128, 0, stream>>>(W2, Wpk, 128, 128);
  gemm_mfma_kernel<<<dim3(Mp / 128, 1), 256, 0, stream>>>(actA, Wpk, hbufH, (float*)nullptr, N, 128, 128);
  aggregate12_kernel<<<aggGrid, 256, 0, stream>>>(row_start, edge_src, hbufH, esB, edB,
                                                  (float*)nullptr, actB16, wes3, wed3, esA, edA, N);

  // ---- layer 3 (aggregate-then-transform, all fp16) ----
  aggregate3_pack_kernel<<<aggGrid, 256, 0, stream>>>(row_start, edge_src, actB16, esA, edA, Zh, N);
  pack_w3r_h_kernel<<<128, 512, 0, stream>>>(W3, W3h);
  gemm_f16_kernel<<<Mp / 64, 256, 0, stream>>>(Zh, W3h, (float*)d_out, N);
}

// Round 11
// 396.718 us; speedup vs baseline: 1.1115x; 1.1115x over previous
//
#include <hip/hip_runtime.h>
#include <hip/hip_bf16.h>
#include <hip/hip_fp16.h>
#include <cstddef>
#include <stdint.h>
#include <math.h>

// ---------------------------------------------------------------------------
// GAT 3-layer forward on MI355X.
//   CSR: memset -> hist -> 3-kernel parallel scan -> fill -> wave bitonic sort
//   prep (1 kernel): folds for all 3 layers + W1/W2 split-bf16 packs + W3r fp16
//   L1: split-bf16 MFMA GEMM (fp16 table) -> attn_fold(x) -> agg12
//       (softmax+gather, emits actA fp32 + L2 es/ed fused)
//   L2: GEMM(actA) -> agg12 (emits actB16 fp16 + L3 es/ed fused)
//   L3: gather actB16 -> z fp16 -> one fp16-MFMA GEMM z@W3r -> d_out
// ---------------------------------------------------------------------------

static __device__ __forceinline__ float lrelu(float x){ return x > 0.f ? x : 0.2f * x; }
static __device__ __forceinline__ float elu_f(float x){ return x > 0.f ? x : expm1f(x); }

typedef __bf16    bf16x8 __attribute__((ext_vector_type(8)));
typedef _Float16  f16x8  __attribute__((ext_vector_type(8)));
typedef float     f32x4  __attribute__((ext_vector_type(4)));

// ============================ CSR build ====================================
__global__ void hist_kernel(const int* __restrict__ dst, int* __restrict__ deg, int E){
  int e = blockIdx.x * blockDim.x + threadIdx.x;
  if (e < E) atomicAdd(&deg[dst[e]], 1);
}

__global__ __launch_bounds__(1024) void scan1_kernel(const int* __restrict__ deg,
    int* __restrict__ partial, int* __restrict__ blocksum, int N){
  __shared__ int wsum[16];
  const int tid = threadIdx.x, lane = tid & 63, wid = tid >> 6;
  const int i = blockIdx.x * 1024 + tid;
  int v = (i < N) ? deg[i] : 0;
  int incl = v;
  #pragma unroll
  for (int off = 1; off < 64; off <<= 1){
    int t = __shfl_up(incl, off);
    if (lane >= off) incl += t;
  }
  if (lane == 63) wsum[wid] = incl;
  __syncthreads();
  if (tid == 0){
    int run = 0;
    #pragma unroll
    for (int w = 0; w < 16; w++){ int t = wsum[w]; wsum[w] = run; run += t; }
    blocksum[blockIdx.x] = run;
  }
  __syncthreads();
  if (i < N) partial[i] = wsum[wid] + incl - v;
}

__global__ void scan2_kernel(int* __restrict__ blocksum, int nb){
  const int lane = threadIdx.x;
  int v = (lane < nb) ? blocksum[lane] : 0;
  int incl = v;
  #pragma unroll
  for (int off = 1; off < 64; off <<= 1){
    int t = __shfl_up(incl, off);
    if (lane >= off) incl += t;
  }
  if (lane < nb) blocksum[lane] = incl - v;
}

__global__ void scan3_kernel(const int* __restrict__ partial, const int* __restrict__ blocksum,
    int* __restrict__ row_start, int* __restrict__ cursor, int N, int E){
  const int i = blockIdx.x * blockDim.x + threadIdx.x;
  if (i < N){
    const int r = partial[i] + blocksum[i >> 10];
    row_start[i] = r;
    cursor[i] = r;
  }
  if (i == 0) row_start[N] = E;
}

__global__ void fill_kernel(const int* __restrict__ src, const int* __restrict__ dst,
    int* __restrict__ cursor, int* __restrict__ edge_src, int E){
  int e = blockIdx.x * blockDim.x + threadIdx.x;
  if (e < E){
    int p = atomicAdd(&cursor[dst[e]], 1);
    edge_src[p] = src[e];
  }
}

// deterministic order: ascending srcs. Wave bitonic for deg<=64 (the norm).
__global__ __launch_bounds__(256) void sort_kernel(
    const int* __restrict__ row_start, int* __restrict__ edge_src, int N){
  const int lane = threadIdx.x & 63;
  const int n = blockIdx.x * 4 + (threadIdx.x >> 6);
  if (n >= N) return;
  const int rs = row_start[n], deg = row_start[n + 1] - rs;
  if (deg <= 1) return;
  if (deg <= 64){
    int v = (lane < deg) ? edge_src[rs + lane] : 0x7FFFFFFF;
    #pragma unroll
    for (int k = 2; k <= 64; k <<= 1){
      #pragma unroll
      for (int j = k >> 1; j >= 1; j >>= 1){
        int partner = __shfl_xor(v, j);
        const bool up = ((lane & k) == 0);
        const bool keepmin = (((lane & j) == 0) == up);
        v = keepmin ? min(v, partner) : max(v, partner);
      }
    }
    if (lane < deg) edge_src[rs + lane] = v;
  } else if (lane == 0){
    for (int i = rs + 1; i < rs + deg; i++){
      int key = edge_src[i];
      int j = i - 1;
      while (j >= rs && edge_src[j] > key){ edge_src[j + 1] = edge_src[j]; j--; }
      edge_src[j + 1] = key;
    }
  }
}

// ====================== split-bf16 packing =================================
static __device__ __forceinline__ uint32_t pack_hi_lo(float a){
  uint32_t u  = __float_as_uint(a);
  uint32_t hb = (u + 0x7FFFu + ((u >> 16) & 1u)) & 0xFFFF0000u;  // bf16 RNE of a
  float lof   = a - __uint_as_float(hb);
  uint32_t ul = __float_as_uint(lof);
  uint32_t lb = (ul + 0x7FFFu + ((ul >> 16) & 1u)) >> 16;        // bf16 RNE of residual
  return (hb >> 16) | (lb << 16);
}

// fold helper: wes[h,k] = sum_d W[k,h*D+d]*a_s[h,d]
static __device__ __forceinline__ void fold_one(int gid, const float* __restrict__ W,
    const float* __restrict__ as_, const float* __restrict__ ad_,
    float* __restrict__ wes, float* __restrict__ wed, int K, int D){
  if (gid >= 4 * K) return;
  int h = gid / K, k = gid - h * K;
  const float* wr = W + (size_t)k * (4 * D) + h * D;
  const float* sa = as_ + h * D;
  const float* da = ad_ + h * D;
  float ss = 0.f, sd = 0.f;
  for (int d = 0; d < D; d++){ float w = wr[d]; ss += w * sa[d]; sd += w * da[d]; }
  wes[h * K + k] = ss;
  wed[h * K + k] = sd;
}

// One fused prep kernel: 3 folds + W1/W2 split-bf16 packs + W3r fp16 pack.
// grid = 374 blocks x 256 threads, task-switched on blockIdx.
__global__ __launch_bounds__(256) void prep_kernel(
    const float* __restrict__ W1, const float* __restrict__ a1s, const float* __restrict__ a1d,
    const float* __restrict__ W2, const float* __restrict__ a2s, const float* __restrict__ a2d,
    const float* __restrict__ W3, const float* __restrict__ a3s, const float* __restrict__ a3d,
    float* __restrict__ wes1, float* __restrict__ wed1,
    float* __restrict__ wes2, float* __restrict__ wed2,
    float* __restrict__ wes3, float* __restrict__ wed3,
    uint32_t* __restrict__ Wpk1, uint32_t* __restrict__ Wpk2, __half* __restrict__ W3h)
{
  const int b = blockIdx.x;
  const int tid = threadIdx.x;
  if (b < 2){                       // fold layer 1: 4*96 ids
    fold_one(b * 256 + tid, W1, a1s, a1d, wes1, wed1, 96, 32);
  } else if (b < 4){                // fold layer 2: 4*128 ids
    fold_one((b - 2) * 256 + tid, W2, a2s, a2d, wes2, wed2, 128, 32);
  } else if (b < 6){                // fold layer 3: 4*128 ids
    fold_one((b - 4) * 256 + tid, W3, a3s, a3d, wes3, wed3, 128, 128);
  } else if (b < 54){               // pack W1 [96,128] -> Wpk1[n*96+k], 12288
    const int gid = (b - 6) * 256 + tid;
    const int n = gid / 96, k = gid - n * 96;
    Wpk1[gid] = pack_hi_lo(W1[(size_t)k * 128 + n]);
  } else if (b < 118){              // pack W2 [128,128] -> Wpk2[n*128+k], 16384
    const int gid = (b - 54) * 256 + tid;
    const int n = gid >> 7, k = gid & 127;
    Wpk2[gid] = pack_hi_lo(W2[(size_t)k * 128 + n]);
  } else {                          // pack W3r fp16: 128x512 = 65536
    const int gid = (b - 118) * 256 + tid;
    const int nout = gid >> 9, kk = gid & 511;
    const int h = kk >> 7, k = kk & 127;
    W3h[gid] = __float2half(0.25f * W3[(size_t)k * 512 + h * 128 + nout]);
  }
}

// ====================== MFMA GEMM (split-bf16, 3 mfma) =====================
union PKU { uint32_t u[4]; bf16x8 v; };

static __device__ __forceinline__ void unpack_frag(const uint4 q0, const uint4 q1,
                                                   bf16x8& hi, bf16x8& lo){
  PKU H, L;
  H.u[0] = (q0.x & 0xFFFFu) | (q0.y << 16);
  H.u[1] = (q0.z & 0xFFFFu) | (q0.w << 16);
  H.u[2] = (q1.x & 0xFFFFu) | (q1.y << 16);
  H.u[3] = (q1.z & 0xFFFFu) | (q1.w << 16);
  L.u[0] = (q0.x >> 16) | (q0.y & 0xFFFF0000u);
  L.u[1] = (q0.z >> 16) | (q0.w & 0xFFFF0000u);
  L.u[2] = (q1.x >> 16) | (q1.y & 0xFFFF0000u);
  L.u[3] = (q1.z >> 16) | (q1.w & 0xFFFF0000u);
  hi = H.v; lo = L.v;
}

// C = A@W (L1/L2). A fp32 [M,K] (packed in-register), Wpk [Nout,K] packed.
__global__ __launch_bounds__(256) void gemm_mfma_kernel(
    const float* __restrict__ A, const uint32_t* __restrict__ Wpk,
    __half* __restrict__ Ch, float* __restrict__ Cf, int M, int K, int Nout)
{
  __shared__ uint32_t Asl[4096];   // [128 rows][32 k] u32, XOR-swizzled
  __shared__ uint32_t Bsl[4096];
  const int tid  = threadIdx.x;
  const int lane = tid & 63;
  const int wid  = tid >> 6;
  const int wm   = (wid >> 1) * 64;
  const int wn   = (wid & 1) * 64;
  const int bm   = blockIdx.x * 128;
  const int bn   = blockIdx.y * 128;
  const int srow = tid >> 3;
  const int skof = (tid & 7) * 4;
  const int fr   = lane & 15;
  const int kg   = (lane >> 4) * 8;

  f32x4 acc[4][4] = {};

  for (int kt = 0; kt < K; kt += 32){
    float4 av[4]; uint4 bv[4];
    #pragma unroll
    for (int it = 0; it < 4; it++){
      const int r = srow + it * 32;
      av[it] = (bm + r < M)
          ? *reinterpret_cast<const float4*>(A + (size_t)(bm + r) * K + kt + skof)
          : make_float4(0.f, 0.f, 0.f, 0.f);
      bv[it] = *reinterpret_cast<const uint4*>(Wpk + (size_t)(bn + r) * K + kt + skof);
    }
    __syncthreads();
    #pragma unroll
    for (int it = 0; it < 4; it++){
      const int r  = srow + it * 32;
      const int sw = (r * 32 + skof) ^ ((r & 7) << 2);
      uint4 pv;
      pv.x = pack_hi_lo(av[it].x); pv.y = pack_hi_lo(av[it].y);
      pv.z = pack_hi_lo(av[it].z); pv.w = pack_hi_lo(av[it].w);
      *reinterpret_cast<uint4*>(&Asl[sw]) = pv;
      *reinterpret_cast<uint4*>(&Bsl[sw]) = bv[it];
    }
    __syncthreads();

    bf16x8 Ah[4], Al[4];
    #pragma unroll
    for (int mf = 0; mf < 4; mf++){
      const int r  = wm + mf * 16 + fr;
      const int b  = r * 32 + kg;
      const int sx = (r & 7) << 2;
      const uint4 q0 = *reinterpret_cast<const uint4*>(&Asl[b ^ sx]);
      const uint4 q1 = *reinterpret_cast<const uint4*>(&Asl[(b + 4) ^ sx]);
      unpack_frag(q0, q1, Ah[mf], Al[mf]);
    }
    #pragma unroll
    for (int nf = 0; nf < 4; nf++){
      const int r  = wn + nf * 16 + fr;
      const int b  = r * 32 + kg;
      const int sx = (r & 7) << 2;
      const uint4 q0 = *reinterpret_cast<const uint4*>(&Bsl[b ^ sx]);
      const uint4 q1 = *reinterpret_cast<const uint4*>(&Bsl[(b + 4) ^ sx]);
      bf16x8 Bh, Bl;
      unpack_frag(q0, q1, Bh, Bl);
      #pragma unroll
      for (int mf = 0; mf < 4; mf++){
        acc[mf][nf] = __builtin_amdgcn_mfma_f32_16x16x32_bf16(Al[mf], Bh, acc[mf][nf], 0, 0, 0);
        acc[mf][nf] = __builtin_amdgcn_mfma_f32_16x16x32_bf16(Ah[mf], Bl, acc[mf][nf], 0, 0, 0);
        acc[mf][nf] = __builtin_amdgcn_mfma_f32_16x16x32_bf16(Ah[mf], Bh, acc[mf][nf], 0, 0, 0);
      }
    }
  }

  #pragma unroll
  for (int mf = 0; mf < 4; mf++){
    #pragma unroll
    for (int nf = 0; nf < 4; nf++){
      const int col = bn + wn + nf * 16 + fr;
      #pragma unroll
      for (int j = 0; j < 4; j++){
        const int row = bm + wm + mf * 16 + (lane >> 4) * 4 + j;
        if (row < M){
          const float v = acc[mf][nf][j];
          if (Ch) Ch[(size_t)row * Nout + col] = __float2half(v);
          if (Cf) Cf[(size_t)row * Nout + col] = v;
        }
      }
    }
  }
}

// ============== fp16-MFMA GEMM for the final z@W3r (K=512) ================
__global__ __launch_bounds__(256) void gemm_f16_kernel(
    const __half* __restrict__ Zh, const __half* __restrict__ W3h,
    float* __restrict__ C, int M)
{
  constexpr int LDA = 40;
  __shared__ __half As[64 * LDA];
  __shared__ __half Bs[128 * LDA];
  const int tid  = threadIdx.x;
  const int lane = tid & 63;
  const int wid  = tid >> 6;
  const int wm   = (wid >> 1) * 32;
  const int wn   = (wid & 1) * 64;
  const int bm   = blockIdx.x * 64;
  const int fr   = lane & 15;
  const int kg   = (lane >> 4) * 8;
  const int arow = tid >> 2;
  const int akc  = (tid & 3) * 8;

  f32x4 acc[2][4] = {};

  for (int kt = 0; kt < 512; kt += 32){
    const uint4 a  = *reinterpret_cast<const uint4*>(Zh  + (size_t)(bm + arow) * 512 + kt + akc);
    const uint4 b0 = *reinterpret_cast<const uint4*>(W3h + (size_t)arow        * 512 + kt + akc);
    const uint4 b1 = *reinterpret_cast<const uint4*>(W3h + (size_t)(arow + 64) * 512 + kt + akc);
    __syncthreads();
    *reinterpret_cast<uint4*>(&As[arow * LDA + akc])        = a;
    *reinterpret_cast<uint4*>(&Bs[arow * LDA + akc])        = b0;
    *reinterpret_cast<uint4*>(&Bs[(arow + 64) * LDA + akc]) = b1;
    __syncthreads();

    f16x8 af[2], bf[4];
    #pragma unroll
    for (int mf = 0; mf < 2; mf++)
      af[mf] = *reinterpret_cast<const f16x8*>(&As[(wm + mf * 16 + fr) * LDA + kg]);
    #pragma unroll
    for (int nf = 0; nf < 4; nf++)
      bf[nf] = *reinterpret_cast<const f16x8*>(&Bs[(wn + nf * 16 + fr) * LDA + kg]);
    #pragma unroll
    for (int mf = 0; mf < 2; mf++)
      #pragma unroll
      for (int nf = 0; nf < 4; nf++)
        acc[mf][nf] = __builtin_amdgcn_mfma_f32_16x16x32_f16(af[mf], bf[nf], acc[mf][nf], 0, 0, 0);
  }

  #pragma unroll
  for (int mf = 0; mf < 2; mf++){
    #pragma unroll
    for (int nf = 0; nf < 4; nf++){
      const int col = wn + nf * 16 + fr;
      #pragma unroll
      for (int j = 0; j < 4; j++){
        const int row = bm + wm + mf * 16 + (lane >> 4) * 4 + j;
        if (row < M) C[(size_t)row * 128 + col] = acc[mf][nf][j];
      }
    }
  }
}

// ================= attention coefs from folded weights (layer 1) ===========
template<int K>
__global__ __launch_bounds__(256) void attn_fold_kernel(
    const float* __restrict__ in, const float* __restrict__ wes, const float* __restrict__ wed,
    float* __restrict__ es, float* __restrict__ ed, int N)
{
  int gid = blockIdx.x * blockDim.x + threadIdx.x;
  int n = gid >> 2, h = gid & 3;
  if (n >= N) return;
  const float* ip = in + (size_t)n * K;
  const float* sp = wes + h * K;
  const float* dp = wed + h * K;
  float ss = 0.f, sd = 0.f;
  #pragma unroll
  for (int d = 0; d < K; d += 4){
    float4 hv = *reinterpret_cast<const float4*>(ip + d);
    float4 sv = *reinterpret_cast<const float4*>(sp + d);
    float4 dv = *reinterpret_cast<const float4*>(dp + d);
    ss += hv.x * sv.x + hv.y * sv.y + hv.z * sv.z + hv.w * sv.w;
    sd += hv.x * dv.x + hv.y * dv.y + hv.z * dv.z + hv.w * dv.w;
  }
  es[n * 4 + h] = ss;
  ed[n * 4 + h] = sd;
}

// ==================== aggregate: layers 1/2 (fp16 table, concat+ELU) =======
// Simple gather (compiler pipelines it best — rounds 8/10 proved manual
// batching regresses). Emits optional fp32 out + optional fp16 out16, and
// FUSED next-layer es/ed.
__global__ __launch_bounds__(256) void aggregate12_kernel(
    const int* __restrict__ row_start, const int* __restrict__ edge_src,
    const __half* __restrict__ hbuf, const float* __restrict__ es, const float* __restrict__ ed,
    float* __restrict__ out, __half* __restrict__ out16,
    const float* __restrict__ wesN, const float* __restrict__ wedN,
    float* __restrict__ esOut, float* __restrict__ edOut, int N)
{
  const int lane = threadIdx.x & 63;
  const int n = blockIdx.x * 4 + (threadIdx.x >> 6);
  if (n >= N) return;
  const int rs  = row_start[n];
  const int deg = row_start[n + 1] - rs;
  const float4 ed4 = *reinterpret_cast<const float4*>(&ed[n * 4]);
  const int sub  = lane >> 4;
  const int cl   = lane & 15;
  const int head = cl >> 2;
  float acc[8] = {0.f, 0.f, 0.f, 0.f, 0.f, 0.f, 0.f, 0.f};

  auto gather = [&](int cnt, int s_reg, float a0, float a1, float a2, float a3){
    for (int j = 0; j < cnt; j += 4){
      const int  el    = j + sub;
      const bool valid = el < cnt;
      const int  ei    = valid ? el : 0;
      const int  s     = __shfl(s_reg, ei);
      const float b0 = __shfl(a0, ei), b1 = __shfl(a1, ei);
      const float b2 = __shfl(a2, ei), b3 = __shfl(a3, ei);
      float al = head == 0 ? b0 : head == 1 ? b1 : head == 2 ? b2 : b3;
      if (!valid) al = 0.f;
      const uint4 raw = *reinterpret_cast<const uint4*>(hbuf + (size_t)s * 128 + cl * 8);
      const __half2* hp = reinterpret_cast<const __half2*>(&raw);
      #pragma unroll
      for (int q = 0; q < 4; q++){
        float2 f = __half22float2(hp[q]);
        acc[q * 2]     = fmaf(f.x, al, acc[q * 2]);
        acc[q * 2 + 1] = fmaf(f.y, al, acc[q * 2 + 1]);
      }
    }
  };

  if (deg <= 64){
    int   s_reg = 0;
    float e0 = -INFINITY, e1 = -INFINITY, e2 = -INFINITY, e3 = -INFINITY;
    if (lane < deg){
      s_reg = edge_src[rs + lane];
      const float4 e4 = *reinterpret_cast<const float4*>(&es[s_reg * 4]);
      e0 = lrelu(e4.x + ed4.x); e1 = lrelu(e4.y + ed4.y);
      e2 = lrelu(e4.z + ed4.z); e3 = lrelu(e4.w + ed4.w);
    }
    float mx0 = e0, mx1 = e1, mx2 = e2, mx3 = e3;
    #pragma unroll
    for (int off = 1; off < 64; off <<= 1){
      mx0 = fmaxf(mx0, __shfl_xor(mx0, off)); mx1 = fmaxf(mx1, __shfl_xor(mx1, off));
      mx2 = fmaxf(mx2, __shfl_xor(mx2, off)); mx3 = fmaxf(mx3, __shfl_xor(mx3, off));
    }
    float p0 = 0.f, p1 = 0.f, p2 = 0.f, p3 = 0.f;
    if (lane < deg){
      p0 = __expf(e0 - mx0); p1 = __expf(e1 - mx1);
      p2 = __expf(e2 - mx2); p3 = __expf(e3 - mx3);
    }
    float s0 = p0, s1 = p1, s2 = p2, s3 = p3;
    #pragma unroll
    for (int off = 1; off < 64; off <<= 1){
      s0 += __shfl_xor(s0, off); s1 += __shfl_xor(s1, off);
      s2 += __shfl_xor(s2, off); s3 += __shfl_xor(s3, off);
    }
    gather(deg, s_reg,
           p0 / (s0 + 1e-16f), p1 / (s1 + 1e-16f),
           p2 / (s2 + 1e-16f), p3 / (s3 + 1e-16f));
  } else {
    float mx0 = -INFINITY, mx1 = -INFINITY, mx2 = -INFINITY, mx3 = -INFINITY;
    for (int i = lane; i < deg; i += 64){
      int s = edge_src[rs + i];
      float4 e4 = *reinterpret_cast<const float4*>(&es[s * 4]);
      mx0 = fmaxf(mx0, lrelu(e4.x + ed4.x)); mx1 = fmaxf(mx1, lrelu(e4.y + ed4.y));
      mx2 = fmaxf(mx2, lrelu(e4.z + ed4.z)); mx3 = fmaxf(mx3, lrelu(e4.w + ed4.w));
    }
    #pragma unroll
    for (int off = 1; off < 64; off <<= 1){
      mx0 = fmaxf(mx0, __shfl_xor(mx0, off)); mx1 = fmaxf(mx1, __shfl_xor(mx1, off));
      mx2 = fmaxf(mx2, __shfl_xor(mx2, off)); mx3 = fmaxf(mx3, __shfl_xor(mx3, off));
    }
    float s0 = 0.f, s1 = 0.f, s2 = 0.f, s3 = 0.f;
    for (int i = lane; i < deg; i += 64){
      int s = edge_src[rs + i];
      float4 e4 = *reinterpret_cast<const float4*>(&es[s * 4]);
      s0 += __expf(lrelu(e4.x + ed4.x) - mx0); s1 += __expf(lrelu(e4.y + ed4.y) - mx1);
      s2 += __expf(lrelu(e4.z + ed4.z) - mx2); s3 += __expf(lrelu(e4.w + ed4.w) - mx3);
    }
    #pragma unroll
    for (int off = 1; off < 64; off <<= 1){
      s0 += __shfl_xor(s0, off); s1 += __shfl_xor(s1, off);
      s2 += __shfl_xor(s2, off); s3 += __shfl_xor(s3, off);
    }
    const float inv0 = 1.f / (s0 + 1e-16f), inv1 = 1.f / (s1 + 1e-16f);
    const float inv2 = 1.f / (s2 + 1e-16f), inv3 = 1.f / (s3 + 1e-16f);
    for (int base = 0; base < deg; base += 64){
      const int cnt = min(64, deg - base);
      int s_reg = 0; float a0 = 0.f, a1 = 0.f, a2 = 0.f, a3 = 0.f;
      if (lane < cnt){
        s_reg = edge_src[rs + base + lane];
        const float4 e4 = *reinterpret_cast<const float4*>(&es[s_reg * 4]);
        a0 = __expf(lrelu(e4.x + ed4.x) - mx0) * inv0;
        a1 = __expf(lrelu(e4.y + ed4.y) - mx1) * inv1;
        a2 = __expf(lrelu(e4.z + ed4.z) - mx2) * inv2;
        a3 = __expf(lrelu(e4.w + ed4.w) - mx3) * inv3;
      }
      gather(cnt, s_reg, a0, a1, a2, a3);
    }
  }

  #pragma unroll
  for (int q = 0; q < 8; q++){
    acc[q] += __shfl_xor(acc[q], 16);
    acc[q] += __shfl_xor(acc[q], 32);
  }
  float o[8];
  #pragma unroll
  for (int q = 0; q < 8; q++) o[q] = elu_f(acc[q]);

  // fused next-layer attention coefs: subgroup h computes es/ed[n,h]
  {
    const int h = sub;
    float ssum = 0.f, dsum = 0.f;
    #pragma unroll
    for (int q = 0; q < 8; q++){
      ssum = fmaf(o[q], wesN[h * 128 + cl * 8 + q], ssum);
      dsum = fmaf(o[q], wedN[h * 128 + cl * 8 + q], dsum);
    }
    #pragma unroll
    for (int off = 1; off < 16; off <<= 1){
      ssum += __shfl_xor(ssum, off);
      dsum += __shfl_xor(dsum, off);
    }
    if (cl == 0){
      esOut[n * 4 + h] = ssum;
      edOut[n * 4 + h] = dsum;
    }
  }

  if (lane < 16){
    if (out){
      *reinterpret_cast<float4*>(&out[(size_t)n * 128 + lane * 8]) =
          make_float4(o[0], o[1], o[2], o[3]);
      *reinterpret_cast<float4*>(&out[(size_t)n * 128 + lane * 8 + 4]) =
          make_float4(o[4], o[5], o[6], o[7]);
    }
    if (out16){
      union { __half2 h2[4]; uint4 u; } pk;
      pk.h2[0] = __floats2half2_rn(o[0], o[1]);
      pk.h2[1] = __floats2half2_rn(o[2], o[3]);
      pk.h2[2] = __floats2half2_rn(o[4], o[5]);
      pk.h2[3] = __floats2half2_rn(o[6], o[7]);
      *reinterpret_cast<uint4*>(&out16[(size_t)n * 128 + lane * 8]) = pk.u;
    }
  }
}

// ========= aggregate layer 3: gather actB16 -> z[N,4,128] fp16 =============
__global__ __launch_bounds__(256) void aggregate3_pack_kernel(
    const int* __restrict__ row_start, const int* __restrict__ edge_src,
    const __half* __restrict__ tbl, const float* __restrict__ es, const float* __restrict__ ed,
    __half* __restrict__ Zh, int N)
{
  const int lane = threadIdx.x & 63;
  const int n = blockIdx.x * 4 + (threadIdx.x >> 6);
  if (n >= N) return;
  const int rs  = row_start[n];
  const int deg = row_start[n + 1] - rs;
  const float4 ed4 = *reinterpret_cast<const float4*>(&ed[n * 4]);
  const int sub = lane >> 4;
  const int cl  = lane & 15;
  float acc[4][8] = {};

  auto gather = [&](int cnt, int s_reg, float a0, float a1, float a2, float a3){
    for (int j = 0; j < cnt; j += 4){
      const int  el    = j + sub;
      const bool valid = el < cnt;
      const int  ei    = valid ? el : 0;
      const int  s     = __shfl(s_reg, ei);
      float al[4];
      al[0] = __shfl(a0, ei); al[1] = __shfl(a1, ei);
      al[2] = __shfl(a2, ei); al[3] = __shfl(a3, ei);
      if (!valid){ al[0] = al[1] = al[2] = al[3] = 0.f; }
      const uint4 raw = *reinterpret_cast<const uint4*>(tbl + (size_t)s * 128 + cl * 8);
      const __half2* hp = reinterpret_cast<const __half2*>(&raw);
      float f[8];
      #pragma unroll
      for (int q = 0; q < 4; q++){
        float2 t = __half22float2(hp[q]);
        f[q * 2] = t.x; f[q * 2 + 1] = t.y;
      }
      #pragma unroll
      for (int h = 0; h < 4; h++)
        #pragma unroll
        for (int q = 0; q < 8; q++)
          acc[h][q] = fmaf(f[q], al[h], acc[h][q]);
    }
  };

  if (deg <= 64){
    int   s_reg = 0;
    float e0 = -INFINITY, e1 = -INFINITY, e2 = -INFINITY, e3 = -INFINITY;
    if (lane < deg){
      s_reg = edge_src[rs + lane];
      const float4 e4 = *reinterpret_cast<const float4*>(&es[s_reg * 4]);
      e0 = lrelu(e4.x + ed4.x); e1 = lrelu(e4.y + ed4.y);
      e2 = lrelu(e4.z + ed4.z); e3 = lrelu(e4.w + ed4.w);
    }
    float mx0 = e0, mx1 = e1, mx2 = e2, mx3 = e3;
    #pragma unroll
    for (int off = 1; off < 64; off <<= 1){
      mx0 = fmaxf(mx0, __shfl_xor(mx0, off)); mx1 = fmaxf(mx1, __shfl_xor(mx1, off));
      mx2 = fmaxf(mx2, __shfl_xor(mx2, off)); mx3 = fmaxf(mx3, __shfl_xor(mx3, off));
    }
    float p0 = 0.f, p1 = 0.f, p2 = 0.f, p3 = 0.f;
    if (lane < deg){
      p0 = __expf(e0 - mx0); p1 = __expf(e1 - mx1);
      p2 = __expf(e2 - mx2); p3 = __expf(e3 - mx3);
    }
    float s0 = p0, s1 = p1, s2 = p2, s3 = p3;
    #pragma unroll
    for (int off = 1; off < 64; off <<= 1){
      s0 += __shfl_xor(s0, off); s1 += __shfl_xor(s1, off);
      s2 += __shfl_xor(s2, off); s3 += __shfl_xor(s3, off);
    }
    gather(deg, s_reg,
           p0 / (s0 + 1e-16f), p1 / (s1 + 1e-16f),
           p2 / (s2 + 1e-16f), p3 / (s3 + 1e-16f));
  } else {
    float mx0 = -INFINITY, mx1 = -INFINITY, mx2 = -INFINITY, mx3 = -INFINITY;
    for (int i = lane; i < deg; i += 64){
      int s = edge_src[rs + i];
      float4 e4 = *reinterpret_cast<const float4*>(&es[s * 4]);
      mx0 = fmaxf(mx0, lrelu(e4.x + ed4.x)); mx1 = fmaxf(mx1, lrelu(e4.y + ed4.y));
      mx2 = fmaxf(mx2, lrelu(e4.z + ed4.z)); mx3 = fmaxf(mx3, lrelu(e4.w + ed4.w));
    }
    #pragma unroll
    for (int off = 1; off < 64; off <<= 1){
      mx0 = fmaxf(mx0, __shfl_xor(mx0, off)); mx1 = fmaxf(mx1, __shfl_xor(mx1, off));
      mx2 = fmaxf(mx2, __shfl_xor(mx2, off)); mx3 = fmaxf(mx3, __shfl_xor(mx3, off));
    }
    float s0 = 0.f, s1 = 0.f, s2 = 0.f, s3 = 0.f;
    for (int i = lane; i < deg; i += 64){
      int s = edge_src[rs + i];
      float4 e4 = *reinterpret_cast<const float4*>(&es[s * 4]);
      s0 += __expf(lrelu(e4.x + ed4.x) - mx0); s1 += __expf(lrelu(e4.y + ed4.y) - mx1);
      s2 += __expf(lrelu(e4.z + ed4.z) - mx2); s3 += __expf(lrelu(e4.w + ed4.w) - mx3);
    }
    #pragma unroll
    for (int off = 1; off < 64; off <<= 1){
      s0 += __shfl_xor(s0, off); s1 += __shfl_xor(s1, off);
      s2 += __shfl_xor(s2, off); s3 += __shfl_xor(s3, off);
    }
    const float inv0 = 1.f / (s0 + 1e-16f), inv1 = 1.f / (s1 + 1e-16f);
    const float inv2 = 1.f / (s2 + 1e-16f), inv3 = 1.f / (s3 + 1e-16f);
    for (int base = 0; base < deg; base += 64){
      const int cnt = min(64, deg - base);
      int s_reg = 0; float a0 = 0.f, a1 = 0.f, a2 = 0.f, a3 = 0.f;
      if (lane < cnt){
        s_reg = edge_src[rs + base + lane];
        const float4 e4 = *reinterpret_cast<const float4*>(&es[s_reg * 4]);
        a0 = __expf(lrelu(e4.x + ed4.x) - mx0) * inv0;
        a1 = __expf(lrelu(e4.y + ed4.y) - mx1) * inv1;
        a2 = __expf(lrelu(e4.z + ed4.z) - mx2) * inv2;
        a3 = __expf(lrelu(e4.w + ed4.w) - mx3) * inv3;
      }
      gather(cnt, s_reg, a0, a1, a2, a3);
    }
  }

  #pragma unroll
  for (int h = 0; h < 4; h++)
    #pragma unroll
    for (int q = 0; q < 8; q++){
      acc[h][q] += __shfl_xor(acc[h][q], 16);
      acc[h][q] += __shfl_xor(acc[h][q], 32);
    }
  if (lane < 16){
    #pragma unroll
    for (int h = 0; h < 4; h++){
      union { __half2 h2[4]; uint4 u; } pk;
      pk.h2[0] = __floats2half2_rn(acc[h][0], acc[h][1]);
      pk.h2[1] = __floats2half2_rn(acc[h][2], acc[h][3]);
      pk.h2[2] = __floats2half2_rn(acc[h][4], acc[h][5]);
      pk.h2[3] = __floats2half2_rn(acc[h][6], acc[h][7]);
      *reinterpret_cast<uint4*>(Zh + (size_t)n * 512 + h * 128 + cl * 8) = pk.u;
    }
  }
}

// =============================== driver ====================================
extern "C" void kernel_launch(void* const* d_in, const int* in_sizes, int n_in,
                              void* d_out, int out_size, void* d_ws, size_t ws_size,
                              hipStream_t stream) {
  const float* x   = (const float*)d_in[0];
  const int*   src = (const int*)  d_in[1];
  const int*   dst = (const int*)  d_in[2];
  const float* W1  = (const float*)d_in[3];
  const float* a1s = (const float*)d_in[4];
  const float* a1d = (const float*)d_in[5];
  const float* W2  = (const float*)d_in[6];
  const float* a2s = (const float*)d_in[7];
  const float* a2d = (const float*)d_in[8];
  const float* W3  = (const float*)d_in[9];
  const float* a3s = (const float*)d_in[10];
  const float* a3d = (const float*)d_in[11];

  const int N  = in_sizes[0] / 96;
  const int E  = in_sizes[1];
  const int Mp = (N + 127) & ~127;
  const int nb = (N + 1023) / 1024;

  char* ws = (char*)d_ws;
  auto alloc = [&](size_t bytes) -> void* {
    void* p = (void*)ws;
    ws += (bytes + 255) & ~(size_t)255;
    return p;
  };
  int*      row_start = (int*)     alloc((size_t)(N + 1) * 4);
  int*      cursor    = (int*)     alloc((size_t)N * 4);
  int*      blocksum  = (int*)     alloc((size_t)1024 * 4);
  int*      edge_src  = (int*)     alloc((size_t)E * 4);
  float*    esA       = (float*)   alloc((size_t)N * 4 * 4);
  float*    edA       = (float*)   alloc((size_t)N * 4 * 4);
  float*    esB       = (float*)   alloc((size_t)N * 4 * 4);
  float*    edB       = (float*)   alloc((size_t)N * 4 * 4);
  float*    wes1      = (float*)   alloc((size_t)4 * 128 * 4);
  float*    wed1      = (float*)   alloc((size_t)4 * 128 * 4);
  float*    wes2      = (float*)   alloc((size_t)4 * 128 * 4);
  float*    wed2      = (float*)   alloc((size_t)4 * 128 * 4);
  float*    wes3      = (float*)   alloc((size_t)4 * 128 * 4);
  float*    wed3      = (float*)   alloc((size_t)4 * 128 * 4);
  __half*   hbufH     = (__half*)  alloc((size_t)N * 128 * 2);   // L1/L2 gather table
  float*    actA      = (float*)   alloc((size_t)N * 128 * 4);
  __half*   actB16    = (__half*)  alloc((size_t)N * 128 * 2);   // L3 gather table
  __half*   Zh        = (__half*)  alloc((size_t)Mp * 512 * 2);  // fp16 z
  __half*   W3h       = (__half*)  alloc((size_t)128 * 512 * 2); // fp16 W3r
  uint32_t* Wpk1      = (uint32_t*)alloc((size_t)128 * 96 * 4);
  uint32_t* Wpk2      = (uint32_t*)alloc((size_t)128 * 128 * 4);

  // ---- CSR build ----
  hipMemsetAsync(cursor, 0, (size_t)N * 4, stream);
  hist_kernel<<<(E + 255) / 256, 256, 0, stream>>>(dst, cursor, E);
  scan1_kernel<<<nb, 1024, 0, stream>>>(cursor, row_start, blocksum, N);
  scan2_kernel<<<1, 64, 0, stream>>>(blocksum, nb);
  scan3_kernel<<<(N + 255) / 256, 256, 0, stream>>>(row_start, blocksum, row_start, cursor, N, E);
  fill_kernel<<<(E + 255) / 256, 256, 0, stream>>>(src, dst, cursor, edge_src, E);
  sort_kernel<<<(N + 3) / 4, 256, 0, stream>>>(row_start, edge_src, N);

  const int aggGrid  = (N + 3) / 4;
  const int attnGrid = (N * 4 + 255) / 256;

  // ---- fused prep: all folds + weight packs (1 dispatch) ----
  prep_kernel<<<374, 256, 0, stream>>>(W1, a1s, a1d, W2, a2s, a2d, W3, a3s, a3d,
                                       wes1, wed1, wes2, wed2, wes3, wed3,
                                       Wpk1, Wpk2, W3h);

  // ---- layer 1: [N,96] @ [96,128] ----
  gemm_mfma_kernel<<<dim3(Mp / 128, 1), 256, 0, stream>>>(x, Wpk1, hbufH, (float*)nullptr, N, 96, 128);
  attn_fold_kernel<96><<<attnGrid, 256, 0, stream>>>(x, wes1, wed1, esA, edA, N);
  aggregate12_kernel<<<aggGrid, 256, 0, stream>>>(row_start, edge_src, hbufH, esA, edA,
                                                  actA, (__half*)nullptr, wes2, wed2, esB, edB, N);

  // ---- layer 2: [N,128] @ [128,128] ----
  gemm_mfma_kernel<<<dim3(Mp / 128, 1), 256, 0, stream>>>(actA, Wpk2, hbufH, (float*)nullptr, N, 128, 128);
  aggregate12_kernel<<<aggGrid, 256, 0, stream>>>(row_start, edge_src, hbufH, esB, edB,
                                                  (float*)nullptr, actB16, wes3, wed3, esA, edA, N);

  // ---- layer 3 (aggregate-then-transform, all fp16) ----
  aggregate3_pack_kernel<<<aggGrid, 256, 0, stream>>>(row_start, edge_src, actB16, esA, edA, Zh, N);
  gemm_f16_kernel<<<Mp / 64, 256, 0, stream>>>(Zh, W3h, (float*)d_out, N);
}